// Round 19
// baseline (307.800 us; speedup 1.0000x reference)
//
#include <hip/hip_runtime.h>
#include <hip/hip_bf16.h>
#include <cstdint>

#define DEVINL __device__ __forceinline__

typedef __attribute__((ext_vector_type(8))) short bf16x8;
typedef __attribute__((ext_vector_type(4))) float f32x4;

// Native RNE f32->bf16 (compiler emits v_cvt_pk_bf16_f32 for pairs).
DEVINL unsigned short bfbits(float f) {
    union { __hip_bfloat16 h; unsigned short s; } v;
    v.h = __float2bfloat16(f);
    return v.s;
}
DEVINL unsigned pk2(float a, float b) {
    return (unsigned)bfbits(a) | ((unsigned)bfbits(b) << 16);
}
DEVINL float bf2f(unsigned short h) {
    union { unsigned u; float f; } v; v.u = ((unsigned)h) << 16;
    return v.f;
}
// Nontemporal load of 4 floats: read-once streams (W, x) bypass L2 residency,
// preserving L2 for re-read activations (xT/act panels). Must use a native
// clang ext_vector_type (HIP_vector_type is rejected by the builtin).
DEVINL f32x4 ntload4(const float* p) {
    return __builtin_nontemporal_load((const f32x4*)p);
}

constexpr int BN = 256, BK = 32;
constexpr int NSP  = 256;         // H*W
constexpr int SBUF = 256 * 32;    // one sB buffer (u16)

// ---------------------------------------------------------------------------
// Transpose + bf16 convert: x[b][2048][256] f32 -> xT[b][256][2048] bf16.
__global__ __launch_bounds__(256)
void xpose(const float* __restrict__ x, unsigned short* __restrict__ xT)
{
    __shared__ float sh[64][65];
    const int b   = blockIdx.y;
    const int kt  = blockIdx.x & 31;     // 2048/64
    const int ntb = blockIdx.x >> 5;     // 256/64
    const int k0 = kt * 64, n0 = ntb * 64;

    const int r = threadIdx.x >> 4;          // 0..15
    const int c = (threadIdx.x & 15) * 4;    // 0..60

    const float* xb = x + ((size_t)b * 2048 + k0) * 256 + n0;
#pragma unroll
    for (int i = 0; i < 4; ++i) {
        f32x4 v = ntload4(xb + (size_t)(r + 16 * i) * 256 + c);   // read-once: nt
        sh[r + 16 * i][c + 0] = v.x;
        sh[r + 16 * i][c + 1] = v.y;
        sh[r + 16 * i][c + 2] = v.z;
        sh[r + 16 * i][c + 3] = v.w;
    }
    __syncthreads();
#pragma unroll
    for (int i = 0; i < 4; ++i) {
        const int rr = r + 16 * i;           // n within tile
        uint2 o;
        o.x = pk2(sh[c + 0][rr], sh[c + 1][rr]);
        o.y = pk2(sh[c + 2][rr], sh[c + 3][rr]);
        *(uint2*)(xT + ((size_t)b * NSP + n0 + rr) * 2048 + k0 + c) = o;
    }
}

// ---------------------------------------------------------------------------
// L1 kernel: BM=256, 1024 threads (16 waves, 4x4 grid of 64x64 wave tiles).
// Proven schedule: sA dbuf [2][256][32], sB dbuf [2][256][32] slot-XOR,
// ONE __syncthreads per K-step, LOADA/GLOADB at step top, STOREA after MFMA,
// native cvt_pk, direct-scatter epilogue. W loads NONTEMPORAL (read-once).
__global__ __launch_bounds__(1024, 1)
void fc_gemm256(const float* __restrict__ Wt, const float* __restrict__ bias,
                const unsigned short* __restrict__ X, unsigned short* __restrict__ Yt,
                int M, int K)
{
    constexpr int BM    = 256;
    constexpr int SABUF = BM * 32;   // 8192 u16

    const int b  = blockIdx.x;
    const int m0 = blockIdx.y * BM;

    __shared__ __align__(128) unsigned short pool[2 * SABUF + 2 * SBUF];  // 65,536 B
    unsigned short* sA = pool;
    unsigned short* sB = pool + 2 * SABUF;

    const int tid  = threadIdx.x;
    const int lane = tid & 63;
    const int wid  = tid >> 6;            // 0..15
    const int wm   = (wid >> 2) * 64;     // wave m-offset (0/64/128/192)
    const int wn   = (wid & 3) * 64;      // wave n-offset
    const int fr   = lane & 15;
    const int fo   = (lane >> 4) * 8;     // k-chunk offset (u16)

    // A staging: 256x32 f32, thread owns row tid>>2, two float4 at (tid&3)*8
    const int am = tid >> 2, ac = (tid & 3) * 8;
    const float* Wb = Wt + (size_t)b * M * K + (size_t)m0 * K + (size_t)am * K + ac;

    // B gload: wave wid covers rows [wid*16, wid*16+16), 1 op x 16 rows
    const int grow = wid * 16 + (lane >> 2);
    const int gchk = ((lane & 3) ^ ((lane >> 3) & 3)) * 8;
    const unsigned short* Xb = X + (size_t)b * NSP * K;

    const int bslot = ((lane >> 4) ^ ((fr >> 1) & 3)) * 8;

    const int NT = K / BK;

    f32x4 aS0, aS1;

#define LOADA(k0) { aS0 = ntload4(Wb + (k0)); \
                    aS1 = ntload4(Wb + (k0) + 4); }
#define STOREA(p) { uint4 w_; \
        w_.x = pk2(aS0.x, aS0.y); w_.y = pk2(aS0.z, aS0.w); \
        w_.z = pk2(aS1.x, aS1.y); w_.w = pk2(aS1.z, aS1.w); \
        *(uint4*)&sA[(p) * SABUF + am * 32 + ac] = w_; }
#define GLOADB(k0, p) { \
        const unsigned short* src_ = Xb + (size_t)grow * K + (k0) + gchk; \
        const unsigned short* dst_ = sB + (p) * SBUF + (wid * 16) * 32; \
        __builtin_amdgcn_global_load_lds( \
            (const __attribute__((address_space(1))) void*)src_, \
            (__attribute__((address_space(3))) void*)dst_, 16, 0, 0); }

    f32x4 acc[4][4] = {};

    GLOADB(0, 0)
    LOADA(0)
    STOREA(0)
    __syncthreads();

#pragma unroll 1
    for (int t = 0; t < NT; ++t) {
        const int p = t & 1;
        if (t + 1 < NT) { LOADA((t + 1) * BK) GLOADB((t + 1) * BK, p ^ 1) }

        bf16x8 af[4], bfv[4];
#pragma unroll
        for (int i = 0; i < 4; ++i)
            af[i] = *(const bf16x8*)&sA[p * SABUF + (wm + i * 16 + fr) * 32 + fo];
#pragma unroll
        for (int i = 0; i < 4; ++i)
            bfv[i] = *(const bf16x8*)&sB[p * SBUF + (wn + i * 16 + fr) * 32 + bslot];

#pragma unroll
        for (int mi = 0; mi < 4; ++mi)
#pragma unroll
            for (int ni = 0; ni < 4; ++ni)
                acc[mi][ni] = __builtin_amdgcn_mfma_f32_16x16x32_bf16(af[mi], bfv[ni], acc[mi][ni], 0, 0, 0);

        if (t + 1 < NT) STOREA(p ^ 1)

        __syncthreads();
    }
#undef LOADA
#undef STOREA
#undef GLOADB

    // Direct-scatter epilogue.
    const int hi4 = (lane >> 4) * 4;
#pragma unroll
    for (int mi = 0; mi < 4; ++mi) {
#pragma unroll
        for (int ni = 0; ni < 4; ++ni) {
            const int n  = wn + ni * 16 + fr;
            const int mb = m0 + wm + mi * 16 + hi4;
            f32x4 v = acc[mi][ni];
            float y[4];
#pragma unroll
            for (int q = 0; q < 4; ++q) {
                float yv = v[q] + bias[(size_t)b * M + mb + q];
                y[q] = 1.0f / (1.0f + __expf(-yv));
            }
            uint2 o;
            o.x = pk2(y[0], y[1]);
            o.y = pk2(y[2], y[3]);
            *(uint2*)&Yt[((size_t)b * NSP + n) * M + mb] = o;
        }
    }
}

// ---------------------------------------------------------------------------
// BM=128 kernel: 512 threads, 8 waves, 2x4 grid of 64x64 tiles. NT W loads.
__global__ __launch_bounds__(512, 2)
void fc_gemm128(const float* __restrict__ Wt, const float* __restrict__ bias,
                const unsigned short* __restrict__ X, unsigned short* __restrict__ Yt,
                int M, int K)
{
    constexpr int BM    = 128;
    constexpr int SABUF = BM * 32;   // 4096 u16

    const int b  = blockIdx.x;
    const int m0 = blockIdx.y * BM;

    __shared__ __align__(128) unsigned short pool[2 * SABUF + 2 * SBUF];  // 49,152 B
    unsigned short* sA = pool;
    unsigned short* sB = pool + 2 * SABUF;

    const int tid  = threadIdx.x;
    const int lane = tid & 63;
    const int wid  = tid >> 6;            // 0..7
    const int wm   = (wid >> 2) * 64;
    const int wn   = (wid & 3) * 64;
    const int fr   = lane & 15;
    const int fo   = (lane >> 4) * 8;

    const int am = tid >> 2, ac = (tid & 3) * 8;
    const float* Wb = Wt + (size_t)b * M * K + (size_t)m0 * K + (size_t)am * K + ac;

    const int grow = wid * 32 + (lane >> 2);
    const int gchk = ((lane & 3) ^ ((lane >> 3) & 3)) * 8;
    const unsigned short* Xb = X + (size_t)b * NSP * K;

    const int bslot = ((lane >> 4) ^ ((fr >> 1) & 3)) * 8;

    const int NT = K / BK;

    f32x4 aS0, aS1;

#define LOADA(k0) { aS0 = ntload4(Wb + (k0)); \
                    aS1 = ntload4(Wb + (k0) + 4); }
#define STOREA(p) { uint4 w_; \
        w_.x = pk2(aS0.x, aS0.y); w_.y = pk2(aS0.z, aS0.w); \
        w_.z = pk2(aS1.x, aS1.y); w_.w = pk2(aS1.z, aS1.w); \
        *(uint4*)&sA[(p) * SABUF + am * 32 + ac] = w_; }
#define GLOADB(k0, p) { \
    _Pragma("unroll") for (int i = 0; i < 2; ++i) { \
        const unsigned short* src_ = Xb + (size_t)(grow + i * 16) * K + (k0) + gchk; \
        const unsigned short* dst_ = sB + (p) * SBUF + (wid * 32 + i * 16) * 32; \
        __builtin_amdgcn_global_load_lds( \
            (const __attribute__((address_space(1))) void*)src_, \
            (__attribute__((address_space(3))) void*)dst_, 16, 0, 0); } }

    f32x4 acc[4][4] = {};

    GLOADB(0, 0)
    LOADA(0)
    STOREA(0)
    __syncthreads();

#pragma unroll 1
    for (int t = 0; t < NT; ++t) {
        const int p = t & 1;
        if (t + 1 < NT) { LOADA((t + 1) * BK) GLOADB((t + 1) * BK, p ^ 1) }

        bf16x8 af[4], bfv[4];
#pragma unroll
        for (int i = 0; i < 4; ++i)
            af[i] = *(const bf16x8*)&sA[p * SABUF + (wm + i * 16 + fr) * 32 + fo];
#pragma unroll
        for (int i = 0; i < 4; ++i)
            bfv[i] = *(const bf16x8*)&sB[p * SBUF + (wn + i * 16 + fr) * 32 + bslot];

#pragma unroll
        for (int mi = 0; mi < 4; ++mi)
#pragma unroll
            for (int ni = 0; ni < 4; ++ni)
                acc[mi][ni] = __builtin_amdgcn_mfma_f32_16x16x32_bf16(af[mi], bfv[ni], acc[mi][ni], 0, 0, 0);

        if (t + 1 < NT) STOREA(p ^ 1)

        __syncthreads();
    }
#undef LOADA
#undef STOREA
#undef GLOADB

    const int hi4 = (lane >> 4) * 4;
#pragma unroll
    for (int mi = 0; mi < 4; ++mi) {
#pragma unroll
        for (int ni = 0; ni < 4; ++ni) {
            const int n  = wn + ni * 16 + fr;
            const int mb = m0 + wm + mi * 16 + hi4;
            f32x4 v = acc[mi][ni];
            float y[4];
#pragma unroll
            for (int q = 0; q < 4; ++q) {
                float yv = v[q] + bias[(size_t)b * M + mb + q];
                y[q] = 1.0f / (1.0f + __expf(-yv));
            }
            uint2 o;
            o.x = pk2(y[0], y[1]);
            o.y = pk2(y[2], y[3]);
            *(uint2*)&Yt[((size_t)b * NSP + n) * M + mb] = o;
        }
    }
}

// ---------------------------------------------------------------------------
// Tail kernel: BM=64, 256 thr, 4 waves x 64x64. NT W loads.
__global__ __launch_bounds__(256, 4)
void fc_gemm(const float* __restrict__ Wt, const float* __restrict__ bias,
             const unsigned short* __restrict__ X, unsigned short* __restrict__ Yt,
             int M, int K)
{
    constexpr int BM    = 64;
    constexpr int SABUF = BM * 32;

    const int b  = blockIdx.x;
    const int m0 = blockIdx.y * BM;

    __shared__ __align__(128) unsigned short pool[2 * SABUF + 2 * SBUF];  // 40,960 B
    unsigned short* sA = pool;
    unsigned short* sB = pool + 2 * SABUF;

    const int tid  = threadIdx.x;
    const int lane = tid & 63;
    const int wid  = tid >> 6;            // 0..3
    const int wn   = wid * 64;
    const int fr   = lane & 15;
    const int fo   = (lane >> 4) * 8;

    const int am = tid >> 2, ac = (tid & 3) * 8;
    const float* Wb = Wt + (size_t)b * M * K + (size_t)m0 * K + (size_t)am * K + ac;

    const int grow = wid * 64 + (lane >> 2);
    const int gchk = ((lane & 3) ^ ((lane >> 3) & 3)) * 8;
    const unsigned short* Xb = X + (size_t)b * NSP * K;

    const int bslot = ((lane >> 4) ^ ((fr >> 1) & 3)) * 8;

    const int NT = K / BK;

    f32x4 aS0, aS1;

#define LOADA(k0) { aS0 = ntload4(Wb + (k0)); \
                    aS1 = ntload4(Wb + (k0) + 4); }
#define STOREA(p) { uint4 w_; \
        w_.x = pk2(aS0.x, aS0.y); w_.y = pk2(aS0.z, aS0.w); \
        w_.z = pk2(aS1.x, aS1.y); w_.w = pk2(aS1.z, aS1.w); \
        *(uint4*)&sA[(p) * SABUF + am * 32 + ac] = w_; }
#define GLOADB(k0, p) { \
    _Pragma("unroll") for (int i = 0; i < 4; ++i) { \
        const unsigned short* src_ = Xb + (size_t)(grow + i * 16) * K + (k0) + gchk; \
        const unsigned short* dst_ = sB + (p) * SBUF + (wid * 64 + i * 16) * 32; \
        __builtin_amdgcn_global_load_lds( \
            (const __attribute__((address_space(1))) void*)src_, \
            (__attribute__((address_space(3))) void*)dst_, 16, 0, 0); } }

    f32x4 acc[4][4] = {};

    GLOADB(0, 0)
    LOADA(0)
    STOREA(0)
    __syncthreads();

#pragma unroll 1
    for (int t = 0; t < NT; ++t) {
        const int p = t & 1;
        if (t + 1 < NT) { LOADA((t + 1) * BK) GLOADB((t + 1) * BK, p ^ 1) }

        bf16x8 af[4], bfv[4];
#pragma unroll
        for (int i = 0; i < 4; ++i)
            af[i] = *(const bf16x8*)&sA[p * SABUF + (i * 16 + fr) * 32 + fo];
#pragma unroll
        for (int i = 0; i < 4; ++i)
            bfv[i] = *(const bf16x8*)&sB[p * SBUF + (wn + i * 16 + fr) * 32 + bslot];

#pragma unroll
        for (int mi = 0; mi < 4; ++mi)
#pragma unroll
            for (int ni = 0; ni < 4; ++ni)
                acc[mi][ni] = __builtin_amdgcn_mfma_f32_16x16x32_bf16(af[mi], bfv[ni], acc[mi][ni], 0, 0, 0);

        if (t + 1 < NT) STOREA(p ^ 1)

        __syncthreads();
    }
#undef LOADA
#undef STOREA
#undef GLOADB

    const int hi4 = (lane >> 4) * 4;
#pragma unroll
    for (int mi = 0; mi < 4; ++mi) {
#pragma unroll
        for (int ni = 0; ni < 4; ++ni) {
            const int n  = wn + ni * 16 + fr;
            const int mb = m0 + mi * 16 + hi4;
            f32x4 v = acc[mi][ni];
            float y[4];
#pragma unroll
            for (int q = 0; q < 4; ++q) {
                float yv = v[q] + bias[(size_t)b * M + mb + q];
                y[q] = 1.0f / (1.0f + __expf(-yv));
            }
            uint2 o;
            o.x = pk2(y[0], y[1]);
            o.y = pk2(y[2], y[3]);
            *(uint2*)&Yt[((size_t)b * NSP + n) * M + mb] = o;
        }
    }
}

// Layer 5: out[b][n] = sum_k act4T[b][n][k] * w5[b][k] + b5[b]   (no sigmoid)
__global__ void fc_final(const unsigned short* __restrict__ A4,
                         const float* __restrict__ W5,
                         const float* __restrict__ B5,
                         float* __restrict__ out)
{
    const int b = blockIdx.x;
    const int t = threadIdx.x;  // 0..255 spatial
    const unsigned short* row = A4 + ((size_t)b * NSP + t) * 128;
    const float* w = W5 + (size_t)b * 128;
    float acc = B5[b];
#pragma unroll
    for (int k = 0; k < 128; k += 8) {
        uint4 v = *(const uint4*)(row + k);
        acc += bf2f((unsigned short)(v.x & 0xffff)) * w[k+0];
        acc += bf2f((unsigned short)(v.x >> 16))    * w[k+1];
        acc += bf2f((unsigned short)(v.y & 0xffff)) * w[k+2];
        acc += bf2f((unsigned short)(v.y >> 16))    * w[k+3];
        acc += bf2f((unsigned short)(v.z & 0xffff)) * w[k+4];
        acc += bf2f((unsigned short)(v.z >> 16))    * w[k+5];
        acc += bf2f((unsigned short)(v.w & 0xffff)) * w[k+6];
        acc += bf2f((unsigned short)(v.w >> 16))    * w[k+7];
    }
    out[b * NSP + t] = acc;
}

extern "C" void kernel_launch(void* const* d_in, const int* in_sizes, int n_in,
                              void* d_out, int out_size, void* d_ws, size_t ws_size,
                              hipStream_t stream)
{
    const float* x  = (const float*)d_in[0];
    const float* w1 = (const float*)d_in[1];
    const float* b1 = (const float*)d_in[2];
    const float* w2 = (const float*)d_in[3];
    const float* b2 = (const float*)d_in[4];
    const float* w3 = (const float*)d_in[5];
    const float* b3 = (const float*)d_in[6];
    const float* w4 = (const float*)d_in[7];
    const float* b4 = (const float*)d_in[8];
    const float* w5 = (const float*)d_in[9];
    const float* b5 = (const float*)d_in[10];

    unsigned short* ws0 = (unsigned short*)d_ws;

    // u16-element offsets. xT dead after L1 -> act2/3/4 reuse its region.
    const size_t XT = (size_t)64 * 256 * 2048;  // 33.55M u16 (67.1 MB)
    unsigned short* xT   = ws0;
    unsigned short* act1 = ws0 + XT;
    unsigned short* act2 = ws0;
    unsigned short* act3 = ws0 + (size_t)64 * 256 * 512;
    unsigned short* act4 = ws0 + (size_t)64 * 256 * (512 + 256);

    xpose<<<dim3(128, 64), dim3(256), 0, stream>>>(x, xT);
    fc_gemm256<<<dim3(64, 4), dim3(1024), 0, stream>>>(w1, b1, xT,   act1, 1024, 2048);
    fc_gemm128<<<dim3(64, 4), dim3(512),  0, stream>>>(w2, b2, act1, act2,  512, 1024);
    fc_gemm<<<dim3(64, 4), dim3(256), 0, stream>>>(w3, b3, act2, act3,  256,  512);
    fc_gemm<<<dim3(64, 2), dim3(256), 0, stream>>>(w4, b4, act3, act4,  128,  256);
    fc_final<<<dim3(64), dim3(256), 0, stream>>>(act4, w5, b5, (float*)d_out);
}

// Round 20
// 305.633 us; speedup vs baseline: 1.0071x; 1.0071x over previous
//
#include <hip/hip_runtime.h>
#include <hip/hip_bf16.h>
#include <cstdint>

#define DEVINL __device__ __forceinline__

typedef __attribute__((ext_vector_type(8))) short bf16x8;
typedef __attribute__((ext_vector_type(4))) float f32x4;

// Native RNE f32->bf16 (compiler emits v_cvt_pk_bf16_f32 for pairs).
DEVINL unsigned short bfbits(float f) {
    union { __hip_bfloat16 h; unsigned short s; } v;
    v.h = __float2bfloat16(f);
    return v.s;
}
DEVINL unsigned pk2(float a, float b) {
    return (unsigned)bfbits(a) | ((unsigned)bfbits(b) << 16);
}
DEVINL float bf2f(unsigned short h) {
    union { unsigned u; float f; } v; v.u = ((unsigned)h) << 16;
    return v.f;
}

constexpr int BN = 256, BK = 32;
constexpr int NSP  = 256;         // H*W
constexpr int SBUF = 256 * 32;    // one sB buffer (u16)

// ---------------------------------------------------------------------------
// Transpose + bf16 convert: x[b][2048][256] f32 -> xT[b][256][2048] bf16.
__global__ __launch_bounds__(256)
void xpose(const float* __restrict__ x, unsigned short* __restrict__ xT)
{
    __shared__ float sh[64][65];
    const int b   = blockIdx.y;
    const int kt  = blockIdx.x & 31;     // 2048/64
    const int ntb = blockIdx.x >> 5;     // 256/64
    const int k0 = kt * 64, n0 = ntb * 64;

    const int r = threadIdx.x >> 4;          // 0..15
    const int c = (threadIdx.x & 15) * 4;    // 0..60

    const float* xb = x + ((size_t)b * 2048 + k0) * 256 + n0;
#pragma unroll
    for (int i = 0; i < 4; ++i) {
        float4 v = *(const float4*)(xb + (size_t)(r + 16 * i) * 256 + c);
        sh[r + 16 * i][c + 0] = v.x;
        sh[r + 16 * i][c + 1] = v.y;
        sh[r + 16 * i][c + 2] = v.z;
        sh[r + 16 * i][c + 3] = v.w;
    }
    __syncthreads();
#pragma unroll
    for (int i = 0; i < 4; ++i) {
        const int rr = r + 16 * i;           // n within tile
        uint2 o;
        o.x = pk2(sh[c + 0][rr], sh[c + 1][rr]);
        o.y = pk2(sh[c + 2][rr], sh[c + 3][rr]);
        *(uint2*)(xT + ((size_t)b * NSP + n0 + rr) * 2048 + k0 + c) = o;
    }
}

// ---------------------------------------------------------------------------
// L1 kernel: BM=256, 1024 threads (16 waves, 4x4 grid of 64x64 wave tiles).
// Proven schedule (R17 best): sA dbuf [2][256][32], sB dbuf [2][256][32]
// slot-XOR, ONE __syncthreads per K-step, LOADA/GLOADB at step top, STOREA
// after MFMA, native cvt_pk, direct-scatter epilogue.
__global__ __launch_bounds__(1024, 1)
void fc_gemm256(const float* __restrict__ Wt, const float* __restrict__ bias,
                const unsigned short* __restrict__ X, unsigned short* __restrict__ Yt,
                int M, int K)
{
    constexpr int BM    = 256;
    constexpr int SABUF = BM * 32;   // 8192 u16

    const int b  = blockIdx.x;
    const int m0 = blockIdx.y * BM;

    __shared__ __align__(128) unsigned short pool[2 * SABUF + 2 * SBUF];  // 65,536 B
    unsigned short* sA = pool;
    unsigned short* sB = pool + 2 * SABUF;

    const int tid  = threadIdx.x;
    const int lane = tid & 63;
    const int wid  = tid >> 6;            // 0..15
    const int wm   = (wid >> 2) * 64;     // wave m-offset (0/64/128/192)
    const int wn   = (wid & 3) * 64;      // wave n-offset
    const int fr   = lane & 15;
    const int fo   = (lane >> 4) * 8;     // k-chunk offset (u16)

    const int am = tid >> 2, ac = (tid & 3) * 8;
    const float* Wb = Wt + (size_t)b * M * K + (size_t)m0 * K + (size_t)am * K + ac;

    const int grow = wid * 16 + (lane >> 2);
    const int gchk = ((lane & 3) ^ ((lane >> 3) & 3)) * 8;
    const unsigned short* Xb = X + (size_t)b * NSP * K;

    const int bslot = ((lane >> 4) ^ ((fr >> 1) & 3)) * 8;

    const int NT = K / BK;

    float4 aS0, aS1;

#define LOADA(k0) { aS0 = *(const float4*)(Wb + (k0)); \
                    aS1 = *(const float4*)(Wb + (k0) + 4); }
#define STOREA(p) { uint4 w_; \
        w_.x = pk2(aS0.x, aS0.y); w_.y = pk2(aS0.z, aS0.w); \
        w_.z = pk2(aS1.x, aS1.y); w_.w = pk2(aS1.z, aS1.w); \
        *(uint4*)&sA[(p) * SABUF + am * 32 + ac] = w_; }
#define GLOADB(k0, p) { \
        const unsigned short* src_ = Xb + (size_t)grow * K + (k0) + gchk; \
        const unsigned short* dst_ = sB + (p) * SBUF + (wid * 16) * 32; \
        __builtin_amdgcn_global_load_lds( \
            (const __attribute__((address_space(1))) void*)src_, \
            (__attribute__((address_space(3))) void*)dst_, 16, 0, 0); }

    f32x4 acc[4][4] = {};

    GLOADB(0, 0)
    LOADA(0)
    STOREA(0)
    __syncthreads();

#pragma unroll 1
    for (int t = 0; t < NT; ++t) {
        const int p = t & 1;
        if (t + 1 < NT) { LOADA((t + 1) * BK) GLOADB((t + 1) * BK, p ^ 1) }

        bf16x8 af[4], bfv[4];
#pragma unroll
        for (int i = 0; i < 4; ++i)
            af[i] = *(const bf16x8*)&sA[p * SABUF + (wm + i * 16 + fr) * 32 + fo];
#pragma unroll
        for (int i = 0; i < 4; ++i)
            bfv[i] = *(const bf16x8*)&sB[p * SBUF + (wn + i * 16 + fr) * 32 + bslot];

#pragma unroll
        for (int mi = 0; mi < 4; ++mi)
#pragma unroll
            for (int ni = 0; ni < 4; ++ni)
                acc[mi][ni] = __builtin_amdgcn_mfma_f32_16x16x32_bf16(af[mi], bfv[ni], acc[mi][ni], 0, 0, 0);

        if (t + 1 < NT) STOREA(p ^ 1)

        __syncthreads();
    }
#undef LOADA
#undef STOREA
#undef GLOADB

    const int hi4 = (lane >> 4) * 4;
#pragma unroll
    for (int mi = 0; mi < 4; ++mi) {
#pragma unroll
        for (int ni = 0; ni < 4; ++ni) {
            const int n  = wn + ni * 16 + fr;
            const int mb = m0 + wm + mi * 16 + hi4;
            f32x4 v = acc[mi][ni];
            float y[4];
#pragma unroll
            for (int q = 0; q < 4; ++q) {
                float yv = v[q] + bias[(size_t)b * M + mb + q];
                y[q] = 1.0f / (1.0f + __expf(-yv));
            }
            uint2 o;
            o.x = pk2(y[0], y[1]);
            o.y = pk2(y[2], y[3]);
            *(uint2*)&Yt[((size_t)b * NSP + n) * M + mb] = o;
        }
    }
}

// ---------------------------------------------------------------------------
// BM=128 kernel (R16-proven): 512 threads, 8 waves, 2x4 grid of 64x64 tiles.
__global__ __launch_bounds__(512, 2)
void fc_gemm128(const float* __restrict__ Wt, const float* __restrict__ bias,
                const unsigned short* __restrict__ X, unsigned short* __restrict__ Yt,
                int M, int K)
{
    constexpr int BM    = 128;
    constexpr int SABUF = BM * 32;   // 4096 u16

    const int b  = blockIdx.x;
    const int m0 = blockIdx.y * BM;

    __shared__ __align__(128) unsigned short pool[2 * SABUF + 2 * SBUF];  // 49,152 B
    unsigned short* sA = pool;
    unsigned short* sB = pool + 2 * SABUF;

    const int tid  = threadIdx.x;
    const int lane = tid & 63;
    const int wid  = tid >> 6;            // 0..7
    const int wm   = (wid >> 2) * 64;
    const int wn   = (wid & 3) * 64;
    const int fr   = lane & 15;
    const int fo   = (lane >> 4) * 8;

    const int am = tid >> 2, ac = (tid & 3) * 8;
    const float* Wb = Wt + (size_t)b * M * K + (size_t)m0 * K + (size_t)am * K + ac;

    const int grow = wid * 32 + (lane >> 2);
    const int gchk = ((lane & 3) ^ ((lane >> 3) & 3)) * 8;
    const unsigned short* Xb = X + (size_t)b * NSP * K;

    const int bslot = ((lane >> 4) ^ ((fr >> 1) & 3)) * 8;

    const int NT = K / BK;

    float4 aS0, aS1;

#define LOADA(k0) { aS0 = *(const float4*)(Wb + (k0)); \
                    aS1 = *(const float4*)(Wb + (k0) + 4); }
#define STOREA(p) { uint4 w_; \
        w_.x = pk2(aS0.x, aS0.y); w_.y = pk2(aS0.z, aS0.w); \
        w_.z = pk2(aS1.x, aS1.y); w_.w = pk2(aS1.z, aS1.w); \
        *(uint4*)&sA[(p) * SABUF + am * 32 + ac] = w_; }
#define GLOADB(k0, p) { \
    _Pragma("unroll") for (int i = 0; i < 2; ++i) { \
        const unsigned short* src_ = Xb + (size_t)(grow + i * 16) * K + (k0) + gchk; \
        const unsigned short* dst_ = sB + (p) * SBUF + (wid * 32 + i * 16) * 32; \
        __builtin_amdgcn_global_load_lds( \
            (const __attribute__((address_space(1))) void*)src_, \
            (__attribute__((address_space(3))) void*)dst_, 16, 0, 0); } }

    f32x4 acc[4][4] = {};

    GLOADB(0, 0)
    LOADA(0)
    STOREA(0)
    __syncthreads();

#pragma unroll 1
    for (int t = 0; t < NT; ++t) {
        const int p = t & 1;
        if (t + 1 < NT) { LOADA((t + 1) * BK) GLOADB((t + 1) * BK, p ^ 1) }

        bf16x8 af[4], bfv[4];
#pragma unroll
        for (int i = 0; i < 4; ++i)
            af[i] = *(const bf16x8*)&sA[p * SABUF + (wm + i * 16 + fr) * 32 + fo];
#pragma unroll
        for (int i = 0; i < 4; ++i)
            bfv[i] = *(const bf16x8*)&sB[p * SBUF + (wn + i * 16 + fr) * 32 + bslot];

#pragma unroll
        for (int mi = 0; mi < 4; ++mi)
#pragma unroll
            for (int ni = 0; ni < 4; ++ni)
                acc[mi][ni] = __builtin_amdgcn_mfma_f32_16x16x32_bf16(af[mi], bfv[ni], acc[mi][ni], 0, 0, 0);

        if (t + 1 < NT) STOREA(p ^ 1)

        __syncthreads();
    }
#undef LOADA
#undef STOREA
#undef GLOADB

    const int hi4 = (lane >> 4) * 4;
#pragma unroll
    for (int mi = 0; mi < 4; ++mi) {
#pragma unroll
        for (int ni = 0; ni < 4; ++ni) {
            const int n  = wn + ni * 16 + fr;
            const int mb = m0 + wm + mi * 16 + hi4;
            f32x4 v = acc[mi][ni];
            float y[4];
#pragma unroll
            for (int q = 0; q < 4; ++q) {
                float yv = v[q] + bias[(size_t)b * M + mb + q];
                y[q] = 1.0f / (1.0f + __expf(-yv));
            }
            uint2 o;
            o.x = pk2(y[0], y[1]);
            o.y = pk2(y[2], y[3]);
            *(uint2*)&Yt[((size_t)b * NSP + n) * M + mb] = o;
        }
    }
}

// ---------------------------------------------------------------------------
// Tail kernel: BM=64, 256 thr, 4 waves x 64x64 (R15-proven).
__global__ __launch_bounds__(256, 4)
void fc_gemm(const float* __restrict__ Wt, const float* __restrict__ bias,
             const unsigned short* __restrict__ X, unsigned short* __restrict__ Yt,
             int M, int K)
{
    constexpr int BM    = 64;
    constexpr int SABUF = BM * 32;

    const int b  = blockIdx.x;
    const int m0 = blockIdx.y * BM;

    __shared__ __align__(128) unsigned short pool[2 * SABUF + 2 * SBUF];  // 40,960 B
    unsigned short* sA = pool;
    unsigned short* sB = pool + 2 * SABUF;

    const int tid  = threadIdx.x;
    const int lane = tid & 63;
    const int wid  = tid >> 6;            // 0..3
    const int wn   = wid * 64;
    const int fr   = lane & 15;
    const int fo   = (lane >> 4) * 8;

    const int am = tid >> 2, ac = (tid & 3) * 8;
    const float* Wb = Wt + (size_t)b * M * K + (size_t)m0 * K + (size_t)am * K + ac;

    const int grow = wid * 64 + (lane >> 2);
    const int gchk = ((lane & 3) ^ ((lane >> 3) & 3)) * 8;
    const unsigned short* Xb = X + (size_t)b * NSP * K;

    const int bslot = ((lane >> 4) ^ ((fr >> 1) & 3)) * 8;

    const int NT = K / BK;

    float4 aS0, aS1;

#define LOADA(k0) { aS0 = *(const float4*)(Wb + (k0)); \
                    aS1 = *(const float4*)(Wb + (k0) + 4); }
#define STOREA(p) { uint4 w_; \
        w_.x = pk2(aS0.x, aS0.y); w_.y = pk2(aS0.z, aS0.w); \
        w_.z = pk2(aS1.x, aS1.y); w_.w = pk2(aS1.z, aS1.w); \
        *(uint4*)&sA[(p) * SABUF + am * 32 + ac] = w_; }
#define GLOADB(k0, p) { \
    _Pragma("unroll") for (int i = 0; i < 4; ++i) { \
        const unsigned short* src_ = Xb + (size_t)(grow + i * 16) * K + (k0) + gchk; \
        const unsigned short* dst_ = sB + (p) * SBUF + (wid * 64 + i * 16) * 32; \
        __builtin_amdgcn_global_load_lds( \
            (const __attribute__((address_space(1))) void*)src_, \
            (__attribute__((address_space(3))) void*)dst_, 16, 0, 0); } }

    f32x4 acc[4][4] = {};

    GLOADB(0, 0)
    LOADA(0)
    STOREA(0)
    __syncthreads();

#pragma unroll 1
    for (int t = 0; t < NT; ++t) {
        const int p = t & 1;
        if (t + 1 < NT) { LOADA((t + 1) * BK) GLOADB((t + 1) * BK, p ^ 1) }

        bf16x8 af[4], bfv[4];
#pragma unroll
        for (int i = 0; i < 4; ++i)
            af[i] = *(const bf16x8*)&sA[p * SABUF + (i * 16 + fr) * 32 + fo];
#pragma unroll
        for (int i = 0; i < 4; ++i)
            bfv[i] = *(const bf16x8*)&sB[p * SBUF + (wn + i * 16 + fr) * 32 + bslot];

#pragma unroll
        for (int mi = 0; mi < 4; ++mi)
#pragma unroll
            for (int ni = 0; ni < 4; ++ni)
                acc[mi][ni] = __builtin_amdgcn_mfma_f32_16x16x32_bf16(af[mi], bfv[ni], acc[mi][ni], 0, 0, 0);

        if (t + 1 < NT) STOREA(p ^ 1)

        __syncthreads();
    }
#undef LOADA
#undef STOREA
#undef GLOADB

    const int hi4 = (lane >> 4) * 4;
#pragma unroll
    for (int mi = 0; mi < 4; ++mi) {
#pragma unroll
        for (int ni = 0; ni < 4; ++ni) {
            const int n  = wn + ni * 16 + fr;
            const int mb = m0 + mi * 16 + hi4;
            f32x4 v = acc[mi][ni];
            float y[4];
#pragma unroll
            for (int q = 0; q < 4; ++q) {
                float yv = v[q] + bias[(size_t)b * M + mb + q];
                y[q] = 1.0f / (1.0f + __expf(-yv));
            }
            uint2 o;
            o.x = pk2(y[0], y[1]);
            o.y = pk2(y[2], y[3]);
            *(uint2*)&Yt[((size_t)b * NSP + n) * M + mb] = o;
        }
    }
}

// ---------------------------------------------------------------------------
// Fused L4+L5: BM=128 = full M4, grid (64,1); fc_gemm128 body for
// act4 = sigmoid(W4 act3 + b4); then stage act4 [128 n][128 m] per phase in
// LDS (pitch 136) and compute out[b][n] = dot(act4[n], w5[b]) + b5[b]
// in-kernel (4 thr/row x 32 elems + shfl_xor reduce).
// Saves: fc_final launch + act4 HBM write & read (8 MB round-trip).
__global__ __launch_bounds__(512, 2)
void fc_gemm_l45(const float* __restrict__ Wt, const float* __restrict__ bias,
                 const unsigned short* __restrict__ X,
                 const float* __restrict__ W5, const float* __restrict__ B5,
                 float* __restrict__ out)
{
    constexpr int BM    = 128;
    constexpr int M     = 128;
    constexpr int K     = 256;
    constexpr int SABUF = BM * 32;   // 4096 u16
    constexpr int EPP   = 136;       // phase-tile pitch (u16)

    const int b = blockIdx.x;

    __shared__ __align__(128) unsigned short pool[2 * SABUF + 2 * SBUF];  // 49,152 B
    unsigned short* sA = pool;
    unsigned short* sB = pool + 2 * SABUF;

    const int tid  = threadIdx.x;
    const int lane = tid & 63;
    const int wid  = tid >> 6;            // 0..7
    const int wm   = (wid >> 2) * 64;
    const int wn   = (wid & 3) * 64;
    const int fr   = lane & 15;
    const int fo   = (lane >> 4) * 8;

    const int am = tid >> 2, ac = (tid & 3) * 8;
    const float* Wb = Wt + (size_t)b * M * K + (size_t)am * K + ac;

    const int grow = wid * 32 + (lane >> 2);
    const int gchk = ((lane & 3) ^ ((lane >> 3) & 3)) * 8;
    const unsigned short* Xb = X + (size_t)b * NSP * K;

    const int bslot = ((lane >> 4) ^ ((fr >> 1) & 3)) * 8;

    const int NT = K / BK;   // 8

    float4 aS0, aS1;

#define LOADA(k0) { aS0 = *(const float4*)(Wb + (k0)); \
                    aS1 = *(const float4*)(Wb + (k0) + 4); }
#define STOREA(p) { uint4 w_; \
        w_.x = pk2(aS0.x, aS0.y); w_.y = pk2(aS0.z, aS0.w); \
        w_.z = pk2(aS1.x, aS1.y); w_.w = pk2(aS1.z, aS1.w); \
        *(uint4*)&sA[(p) * SABUF + am * 32 + ac] = w_; }
#define GLOADB(k0, p) { \
    _Pragma("unroll") for (int i = 0; i < 2; ++i) { \
        const unsigned short* src_ = Xb + (size_t)(grow + i * 16) * K + (k0) + gchk; \
        const unsigned short* dst_ = sB + (p) * SBUF + (wid * 32 + i * 16) * 32; \
        __builtin_amdgcn_global_load_lds( \
            (const __attribute__((address_space(1))) void*)src_, \
            (__attribute__((address_space(3))) void*)dst_, 16, 0, 0); } }

    f32x4 acc[4][4] = {};

    GLOADB(0, 0)
    LOADA(0)
    STOREA(0)
    __syncthreads();

#pragma unroll 1
    for (int t = 0; t < NT; ++t) {
        const int p = t & 1;
        if (t + 1 < NT) { LOADA((t + 1) * BK) GLOADB((t + 1) * BK, p ^ 1) }

        bf16x8 af[4], bfv[4];
#pragma unroll
        for (int i = 0; i < 4; ++i)
            af[i] = *(const bf16x8*)&sA[p * SABUF + (wm + i * 16 + fr) * 32 + fo];
#pragma unroll
        for (int i = 0; i < 4; ++i)
            bfv[i] = *(const bf16x8*)&sB[p * SBUF + (wn + i * 16 + fr) * 32 + bslot];

#pragma unroll
        for (int mi = 0; mi < 4; ++mi)
#pragma unroll
            for (int ni = 0; ni < 4; ++ni)
                acc[mi][ni] = __builtin_amdgcn_mfma_f32_16x16x32_bf16(af[mi], bfv[ni], acc[mi][ni], 0, 0, 0);

        if (t + 1 < NT) STOREA(p ^ 1)

        __syncthreads();
    }
#undef LOADA
#undef STOREA
#undef GLOADB

    // Fused epilogue: two 128-row phases. Phase ph: waves with (wn>>7)==ph
    // write their sigmoid'd quarter tiles to pool[r][mb] (pitch 136), then all
    // 512 threads dot 32 elems each (4 threads/row) + shfl_xor reduce.
    const int hi4 = (lane >> 4) * 4;
    const float* w5b = W5 + (size_t)b * 128;
    const float  b5v = B5[b];
#pragma unroll 1
    for (int ph = 0; ph < 2; ++ph) {
        __syncthreads();   // prior-phase reads (or K-loop) complete before overwrite
        if ((wn >> 7) == ph) {
#pragma unroll
            for (int mi = 0; mi < 4; ++mi) {
#pragma unroll
                for (int ni = 0; ni < 4; ++ni) {
                    const int r  = (wn & 127) + ni * 16 + fr;   // n within phase
                    const int mb = wm + mi * 16 + hi4;
                    f32x4 v = acc[mi][ni];
                    float y[4];
#pragma unroll
                    for (int q = 0; q < 4; ++q) {
                        float yv = v[q] + bias[(size_t)b * M + mb + q];
                        y[q] = 1.0f / (1.0f + __expf(-yv));
                    }
                    uint2 o;
                    o.x = pk2(y[0], y[1]);
                    o.y = pk2(y[2], y[3]);
                    *(uint2*)&pool[r * EPP + mb] = o;
                }
            }
        }
        __syncthreads();
        const int r = tid >> 2;          // 0..127 (row within phase)
        const int q = tid & 3;           // 32-elem quarter
        const unsigned short* rowp = &pool[r * EPP + q * 32];
        const float* wq = w5b + q * 32;
        float s = 0.0f;
#pragma unroll
        for (int k = 0; k < 32; k += 8) {
            uint4 v = *(const uint4*)(rowp + k);
            s += bf2f((unsigned short)(v.x & 0xffff)) * wq[k + 0];
            s += bf2f((unsigned short)(v.x >> 16))    * wq[k + 1];
            s += bf2f((unsigned short)(v.y & 0xffff)) * wq[k + 2];
            s += bf2f((unsigned short)(v.y >> 16))    * wq[k + 3];
            s += bf2f((unsigned short)(v.z & 0xffff)) * wq[k + 4];
            s += bf2f((unsigned short)(v.z >> 16))    * wq[k + 5];
            s += bf2f((unsigned short)(v.w & 0xffff)) * wq[k + 6];
            s += bf2f((unsigned short)(v.w >> 16))    * wq[k + 7];
        }
        s += __shfl_xor(s, 1);
        s += __shfl_xor(s, 2);
        if (q == 0)
            out[(size_t)b * NSP + ph * 128 + r] = s + b5v;
    }
}

extern "C" void kernel_launch(void* const* d_in, const int* in_sizes, int n_in,
                              void* d_out, int out_size, void* d_ws, size_t ws_size,
                              hipStream_t stream)
{
    const float* x  = (const float*)d_in[0];
    const float* w1 = (const float*)d_in[1];
    const float* b1 = (const float*)d_in[2];
    const float* w2 = (const float*)d_in[3];
    const float* b2 = (const float*)d_in[4];
    const float* w3 = (const float*)d_in[5];
    const float* b3 = (const float*)d_in[6];
    const float* w4 = (const float*)d_in[7];
    const float* b4 = (const float*)d_in[8];
    const float* w5 = (const float*)d_in[9];
    const float* b5 = (const float*)d_in[10];

    unsigned short* ws0 = (unsigned short*)d_ws;

    // u16-element offsets. xT dead after L1 -> act2/3 reuse its region.
    const size_t XT = (size_t)64 * 256 * 2048;  // 33.55M u16 (67.1 MB)
    unsigned short* xT   = ws0;
    unsigned short* act1 = ws0 + XT;
    unsigned short* act2 = ws0;
    unsigned short* act3 = ws0 + (size_t)64 * 256 * 512;

    xpose<<<dim3(128, 64), dim3(256), 0, stream>>>(x, xT);
    fc_gemm256<<<dim3(64, 4), dim3(1024), 0, stream>>>(w1, b1, xT,   act1, 1024, 2048);
    fc_gemm128<<<dim3(64, 4), dim3(512),  0, stream>>>(w2, b2, act1, act2,  512, 1024);
    fc_gemm<<<dim3(64, 4), dim3(256), 0, stream>>>(w3, b3, act2, act3,  256,  512);
    fc_gemm_l45<<<dim3(64), dim3(512), 0, stream>>>(w4, b4, act3, w5, b5, (float*)d_out);
}

// Round 21
// 303.616 us; speedup vs baseline: 1.0138x; 1.0066x over previous
//
#include <hip/hip_runtime.h>
#include <hip/hip_bf16.h>
#include <cstdint>

#define DEVINL __device__ __forceinline__

typedef __attribute__((ext_vector_type(8))) short bf16x8;
typedef __attribute__((ext_vector_type(4))) float f32x4;

// Native RNE f32->bf16 (compiler emits v_cvt_pk_bf16_f32 for pairs).
DEVINL unsigned short bfbits(float f) {
    union { __hip_bfloat16 h; unsigned short s; } v;
    v.h = __float2bfloat16(f);
    return v.s;
}
DEVINL unsigned pk2(float a, float b) {
    return (unsigned)bfbits(a) | ((unsigned)bfbits(b) << 16);
}
DEVINL float bf2f(unsigned short h) {
    union { unsigned u; float f; } v; v.u = ((unsigned)h) << 16;
    return v.f;
}

constexpr int BN = 256, BK = 32;
constexpr int NSP  = 256;         // H*W
constexpr int SBUF = 256 * 32;    // one sB buffer (u16)

// ---------------------------------------------------------------------------
// Transpose + bf16 convert: x[b][2048][256] f32 -> xT[b][256][2048] bf16.
__global__ __launch_bounds__(256)
void xpose(const float* __restrict__ x, unsigned short* __restrict__ xT)
{
    __shared__ float sh[64][65];
    const int b   = blockIdx.y;
    const int kt  = blockIdx.x & 31;     // 2048/64
    const int ntb = blockIdx.x >> 5;     // 256/64
    const int k0 = kt * 64, n0 = ntb * 64;

    const int r = threadIdx.x >> 4;          // 0..15
    const int c = (threadIdx.x & 15) * 4;    // 0..60

    const float* xb = x + ((size_t)b * 2048 + k0) * 256 + n0;
#pragma unroll
    for (int i = 0; i < 4; ++i) {
        float4 v = *(const float4*)(xb + (size_t)(r + 16 * i) * 256 + c);
        sh[r + 16 * i][c + 0] = v.x;
        sh[r + 16 * i][c + 1] = v.y;
        sh[r + 16 * i][c + 2] = v.z;
        sh[r + 16 * i][c + 3] = v.w;
    }
    __syncthreads();
#pragma unroll
    for (int i = 0; i < 4; ++i) {
        const int rr = r + 16 * i;           // n within tile
        uint2 o;
        o.x = pk2(sh[c + 0][rr], sh[c + 1][rr]);
        o.y = pk2(sh[c + 2][rr], sh[c + 3][rr]);
        *(uint2*)(xT + ((size_t)b * NSP + n0 + rr) * 2048 + k0 + c) = o;
    }
}

// ---------------------------------------------------------------------------
// L1 kernel: BM=256, 1024 threads (16 waves, 4x4 grid of 64x64 wave tiles).
// Proven schedule (R17 best): sA dbuf [2][256][32], sB dbuf [2][256][32]
// slot-XOR, ONE __syncthreads per K-step, LOADA/GLOADB at step top, STOREA
// after MFMA, native cvt_pk, direct-scatter epilogue.
__global__ __launch_bounds__(1024, 1)
void fc_gemm256(const float* __restrict__ Wt, const float* __restrict__ bias,
                const unsigned short* __restrict__ X, unsigned short* __restrict__ Yt,
                int M, int K)
{
    constexpr int BM    = 256;
    constexpr int SABUF = BM * 32;   // 8192 u16

    const int b  = blockIdx.x;
    const int m0 = blockIdx.y * BM;

    __shared__ __align__(128) unsigned short pool[2 * SABUF + 2 * SBUF];  // 65,536 B
    unsigned short* sA = pool;
    unsigned short* sB = pool + 2 * SABUF;

    const int tid  = threadIdx.x;
    const int lane = tid & 63;
    const int wid  = tid >> 6;            // 0..15
    const int wm   = (wid >> 2) * 64;     // wave m-offset (0/64/128/192)
    const int wn   = (wid & 3) * 64;      // wave n-offset
    const int fr   = lane & 15;
    const int fo   = (lane >> 4) * 8;     // k-chunk offset (u16)

    const int am = tid >> 2, ac = (tid & 3) * 8;
    const float* Wb = Wt + (size_t)b * M * K + (size_t)m0 * K + (size_t)am * K + ac;

    const int grow = wid * 16 + (lane >> 2);
    const int gchk = ((lane & 3) ^ ((lane >> 3) & 3)) * 8;
    const unsigned short* Xb = X + (size_t)b * NSP * K;

    const int bslot = ((lane >> 4) ^ ((fr >> 1) & 3)) * 8;

    const int NT = K / BK;

    float4 aS0, aS1;

#define LOADA(k0) { aS0 = *(const float4*)(Wb + (k0)); \
                    aS1 = *(const float4*)(Wb + (k0) + 4); }
#define STOREA(p) { uint4 w_; \
        w_.x = pk2(aS0.x, aS0.y); w_.y = pk2(aS0.z, aS0.w); \
        w_.z = pk2(aS1.x, aS1.y); w_.w = pk2(aS1.z, aS1.w); \
        *(uint4*)&sA[(p) * SABUF + am * 32 + ac] = w_; }
#define GLOADB(k0, p) { \
        const unsigned short* src_ = Xb + (size_t)grow * K + (k0) + gchk; \
        const unsigned short* dst_ = sB + (p) * SBUF + (wid * 16) * 32; \
        __builtin_amdgcn_global_load_lds( \
            (const __attribute__((address_space(1))) void*)src_, \
            (__attribute__((address_space(3))) void*)dst_, 16, 0, 0); }

    f32x4 acc[4][4] = {};

    GLOADB(0, 0)
    LOADA(0)
    STOREA(0)
    __syncthreads();

#pragma unroll 1
    for (int t = 0; t < NT; ++t) {
        const int p = t & 1;
        if (t + 1 < NT) { LOADA((t + 1) * BK) GLOADB((t + 1) * BK, p ^ 1) }

        bf16x8 af[4], bfv[4];
#pragma unroll
        for (int i = 0; i < 4; ++i)
            af[i] = *(const bf16x8*)&sA[p * SABUF + (wm + i * 16 + fr) * 32 + fo];
#pragma unroll
        for (int i = 0; i < 4; ++i)
            bfv[i] = *(const bf16x8*)&sB[p * SBUF + (wn + i * 16 + fr) * 32 + bslot];

#pragma unroll
        for (int mi = 0; mi < 4; ++mi)
#pragma unroll
            for (int ni = 0; ni < 4; ++ni)
                acc[mi][ni] = __builtin_amdgcn_mfma_f32_16x16x32_bf16(af[mi], bfv[ni], acc[mi][ni], 0, 0, 0);

        if (t + 1 < NT) STOREA(p ^ 1)

        __syncthreads();
    }
#undef LOADA
#undef STOREA
#undef GLOADB

    const int hi4 = (lane >> 4) * 4;
#pragma unroll
    for (int mi = 0; mi < 4; ++mi) {
#pragma unroll
        for (int ni = 0; ni < 4; ++ni) {
            const int n  = wn + ni * 16 + fr;
            const int mb = m0 + wm + mi * 16 + hi4;
            f32x4 v = acc[mi][ni];
            float y[4];
#pragma unroll
            for (int q = 0; q < 4; ++q) {
                float yv = v[q] + bias[(size_t)b * M + mb + q];
                y[q] = 1.0f / (1.0f + __expf(-yv));
            }
            uint2 o;
            o.x = pk2(y[0], y[1]);
            o.y = pk2(y[2], y[3]);
            *(uint2*)&Yt[((size_t)b * NSP + n) * M + mb] = o;
        }
    }
}

// ---------------------------------------------------------------------------
// BM=128 kernel (R16-proven): 512 threads, 8 waves, 2x4 grid of 64x64 tiles.
__global__ __launch_bounds__(512, 2)
void fc_gemm128(const float* __restrict__ Wt, const float* __restrict__ bias,
                const unsigned short* __restrict__ X, unsigned short* __restrict__ Yt,
                int M, int K)
{
    constexpr int BM    = 128;
    constexpr int SABUF = BM * 32;   // 4096 u16

    const int b  = blockIdx.x;
    const int m0 = blockIdx.y * BM;

    __shared__ __align__(128) unsigned short pool[2 * SABUF + 2 * SBUF];  // 49,152 B
    unsigned short* sA = pool;
    unsigned short* sB = pool + 2 * SABUF;

    const int tid  = threadIdx.x;
    const int lane = tid & 63;
    const int wid  = tid >> 6;            // 0..7
    const int wm   = (wid >> 2) * 64;
    const int wn   = (wid & 3) * 64;
    const int fr   = lane & 15;
    const int fo   = (lane >> 4) * 8;

    const int am = tid >> 2, ac = (tid & 3) * 8;
    const float* Wb = Wt + (size_t)b * M * K + (size_t)m0 * K + (size_t)am * K + ac;

    const int grow = wid * 32 + (lane >> 2);
    const int gchk = ((lane & 3) ^ ((lane >> 3) & 3)) * 8;
    const unsigned short* Xb = X + (size_t)b * NSP * K;

    const int bslot = ((lane >> 4) ^ ((fr >> 1) & 3)) * 8;

    const int NT = K / BK;

    float4 aS0, aS1;

#define LOADA(k0) { aS0 = *(const float4*)(Wb + (k0)); \
                    aS1 = *(const float4*)(Wb + (k0) + 4); }
#define STOREA(p) { uint4 w_; \
        w_.x = pk2(aS0.x, aS0.y); w_.y = pk2(aS0.z, aS0.w); \
        w_.z = pk2(aS1.x, aS1.y); w_.w = pk2(aS1.z, aS1.w); \
        *(uint4*)&sA[(p) * SABUF + am * 32 + ac] = w_; }
#define GLOADB(k0, p) { \
    _Pragma("unroll") for (int i = 0; i < 2; ++i) { \
        const unsigned short* src_ = Xb + (size_t)(grow + i * 16) * K + (k0) + gchk; \
        const unsigned short* dst_ = sB + (p) * SBUF + (wid * 32 + i * 16) * 32; \
        __builtin_amdgcn_global_load_lds( \
            (const __attribute__((address_space(1))) void*)src_, \
            (__attribute__((address_space(3))) void*)dst_, 16, 0, 0); } }

    f32x4 acc[4][4] = {};

    GLOADB(0, 0)
    LOADA(0)
    STOREA(0)
    __syncthreads();

#pragma unroll 1
    for (int t = 0; t < NT; ++t) {
        const int p = t & 1;
        if (t + 1 < NT) { LOADA((t + 1) * BK) GLOADB((t + 1) * BK, p ^ 1) }

        bf16x8 af[4], bfv[4];
#pragma unroll
        for (int i = 0; i < 4; ++i)
            af[i] = *(const bf16x8*)&sA[p * SABUF + (wm + i * 16 + fr) * 32 + fo];
#pragma unroll
        for (int i = 0; i < 4; ++i)
            bfv[i] = *(const bf16x8*)&sB[p * SBUF + (wn + i * 16 + fr) * 32 + bslot];

#pragma unroll
        for (int mi = 0; mi < 4; ++mi)
#pragma unroll
            for (int ni = 0; ni < 4; ++ni)
                acc[mi][ni] = __builtin_amdgcn_mfma_f32_16x16x32_bf16(af[mi], bfv[ni], acc[mi][ni], 0, 0, 0);

        if (t + 1 < NT) STOREA(p ^ 1)

        __syncthreads();
    }
#undef LOADA
#undef STOREA
#undef GLOADB

    const int hi4 = (lane >> 4) * 4;
#pragma unroll
    for (int mi = 0; mi < 4; ++mi) {
#pragma unroll
        for (int ni = 0; ni < 4; ++ni) {
            const int n  = wn + ni * 16 + fr;
            const int mb = m0 + wm + mi * 16 + hi4;
            f32x4 v = acc[mi][ni];
            float y[4];
#pragma unroll
            for (int q = 0; q < 4; ++q) {
                float yv = v[q] + bias[(size_t)b * M + mb + q];
                y[q] = 1.0f / (1.0f + __expf(-yv));
            }
            uint2 o;
            o.x = pk2(y[0], y[1]);
            o.y = pk2(y[2], y[3]);
            *(uint2*)&Yt[((size_t)b * NSP + n) * M + mb] = o;
        }
    }
}

// ---------------------------------------------------------------------------
// Tail kernel: BM=64, 256 thr, 4 waves x 64x64 (R15-proven).
__global__ __launch_bounds__(256, 4)
void fc_gemm(const float* __restrict__ Wt, const float* __restrict__ bias,
             const unsigned short* __restrict__ X, unsigned short* __restrict__ Yt,
             int M, int K)
{
    constexpr int BM    = 64;
    constexpr int SABUF = BM * 32;

    const int b  = blockIdx.x;
    const int m0 = blockIdx.y * BM;

    __shared__ __align__(128) unsigned short pool[2 * SABUF + 2 * SBUF];  // 40,960 B
    unsigned short* sA = pool;
    unsigned short* sB = pool + 2 * SABUF;

    const int tid  = threadIdx.x;
    const int lane = tid & 63;
    const int wid  = tid >> 6;            // 0..3
    const int wn   = wid * 64;
    const int fr   = lane & 15;
    const int fo   = (lane >> 4) * 8;

    const int am = tid >> 2, ac = (tid & 3) * 8;
    const float* Wb = Wt + (size_t)b * M * K + (size_t)m0 * K + (size_t)am * K + ac;

    const int grow = wid * 64 + (lane >> 2);
    const int gchk = ((lane & 3) ^ ((lane >> 3) & 3)) * 8;
    const unsigned short* Xb = X + (size_t)b * NSP * K;

    const int bslot = ((lane >> 4) ^ ((fr >> 1) & 3)) * 8;

    const int NT = K / BK;

    float4 aS0, aS1;

#define LOADA(k0) { aS0 = *(const float4*)(Wb + (k0)); \
                    aS1 = *(const float4*)(Wb + (k0) + 4); }
#define STOREA(p) { uint4 w_; \
        w_.x = pk2(aS0.x, aS0.y); w_.y = pk2(aS0.z, aS0.w); \
        w_.z = pk2(aS1.x, aS1.y); w_.w = pk2(aS1.z, aS1.w); \
        *(uint4*)&sA[(p) * SABUF + am * 32 + ac] = w_; }
#define GLOADB(k0, p) { \
    _Pragma("unroll") for (int i = 0; i < 4; ++i) { \
        const unsigned short* src_ = Xb + (size_t)(grow + i * 16) * K + (k0) + gchk; \
        const unsigned short* dst_ = sB + (p) * SBUF + (wid * 64 + i * 16) * 32; \
        __builtin_amdgcn_global_load_lds( \
            (const __attribute__((address_space(1))) void*)src_, \
            (__attribute__((address_space(3))) void*)dst_, 16, 0, 0); } }

    f32x4 acc[4][4] = {};

    GLOADB(0, 0)
    LOADA(0)
    STOREA(0)
    __syncthreads();

#pragma unroll 1
    for (int t = 0; t < NT; ++t) {
        const int p = t & 1;
        if (t + 1 < NT) { LOADA((t + 1) * BK) GLOADB((t + 1) * BK, p ^ 1) }

        bf16x8 af[4], bfv[4];
#pragma unroll
        for (int i = 0; i < 4; ++i)
            af[i] = *(const bf16x8*)&sA[p * SABUF + (i * 16 + fr) * 32 + fo];
#pragma unroll
        for (int i = 0; i < 4; ++i)
            bfv[i] = *(const bf16x8*)&sB[p * SBUF + (wn + i * 16 + fr) * 32 + bslot];

#pragma unroll
        for (int mi = 0; mi < 4; ++mi)
#pragma unroll
            for (int ni = 0; ni < 4; ++ni)
                acc[mi][ni] = __builtin_amdgcn_mfma_f32_16x16x32_bf16(af[mi], bfv[ni], acc[mi][ni], 0, 0, 0);

        if (t + 1 < NT) STOREA(p ^ 1)

        __syncthreads();
    }
#undef LOADA
#undef STOREA
#undef GLOADB

    const int hi4 = (lane >> 4) * 4;
#pragma unroll
    for (int mi = 0; mi < 4; ++mi) {
#pragma unroll
        for (int ni = 0; ni < 4; ++ni) {
            const int n  = wn + ni * 16 + fr;
            const int mb = m0 + mi * 16 + hi4;
            f32x4 v = acc[mi][ni];
            float y[4];
#pragma unroll
            for (int q = 0; q < 4; ++q) {
                float yv = v[q] + bias[(size_t)b * M + mb + q];
                y[q] = 1.0f / (1.0f + __expf(-yv));
            }
            uint2 o;
            o.x = pk2(y[0], y[1]);
            o.y = pk2(y[2], y[3]);
            *(uint2*)&Yt[((size_t)b * NSP + n) * M + mb] = o;
        }
    }
}

// Layer 5: out[b][n] = sum_k act4T[b][n][k] * w5[b][k] + b5[b]   (no sigmoid)
__global__ void fc_final(const unsigned short* __restrict__ A4,
                         const float* __restrict__ W5,
                         const float* __restrict__ B5,
                         float* __restrict__ out)
{
    const int b = blockIdx.x;
    const int t = threadIdx.x;  // 0..255 spatial
    const unsigned short* row = A4 + ((size_t)b * NSP + t) * 128;
    const float* w = W5 + (size_t)b * 128;
    float acc = B5[b];
#pragma unroll
    for (int k = 0; k < 128; k += 8) {
        uint4 v = *(const uint4*)(row + k);
        acc += bf2f((unsigned short)(v.x & 0xffff)) * w[k+0];
        acc += bf2f((unsigned short)(v.x >> 16))    * w[k+1];
        acc += bf2f((unsigned short)(v.y & 0xffff)) * w[k+2];
        acc += bf2f((unsigned short)(v.y >> 16))    * w[k+3];
        acc += bf2f((unsigned short)(v.z & 0xffff)) * w[k+4];
        acc += bf2f((unsigned short)(v.z >> 16))    * w[k+5];
        acc += bf2f((unsigned short)(v.w & 0xffff)) * w[k+6];
        acc += bf2f((unsigned short)(v.w >> 16))    * w[k+7];
    }
    out[b * NSP + t] = acc;
}

extern "C" void kernel_launch(void* const* d_in, const int* in_sizes, int n_in,
                              void* d_out, int out_size, void* d_ws, size_t ws_size,
                              hipStream_t stream)
{
    const float* x  = (const float*)d_in[0];
    const float* w1 = (const float*)d_in[1];
    const float* b1 = (const float*)d_in[2];
    const float* w2 = (const float*)d_in[3];
    const float* b2 = (const float*)d_in[4];
    const float* w3 = (const float*)d_in[5];
    const float* b3 = (const float*)d_in[6];
    const float* w4 = (const float*)d_in[7];
    const float* b4 = (const float*)d_in[8];
    const float* w5 = (const float*)d_in[9];
    const float* b5 = (const float*)d_in[10];

    unsigned short* ws0 = (unsigned short*)d_ws;

    // u16-element offsets. xT dead after L1 -> act2/3/4 reuse its region.
    const size_t XT = (size_t)64 * 256 * 2048;  // 33.55M u16 (67.1 MB)
    unsigned short* xT   = ws0;
    unsigned short* act1 = ws0 + XT;
    unsigned short* act2 = ws0;
    unsigned short* act3 = ws0 + (size_t)64 * 256 * 512;
    unsigned short* act4 = ws0 + (size_t)64 * 256 * (512 + 256);

    xpose<<<dim3(128, 64), dim3(256), 0, stream>>>(x, xT);
    fc_gemm256<<<dim3(64, 4), dim3(1024), 0, stream>>>(w1, b1, xT,   act1, 1024, 2048);
    fc_gemm128<<<dim3(64, 4), dim3(512),  0, stream>>>(w2, b2, act1, act2,  512, 1024);
    fc_gemm<<<dim3(64, 4), dim3(256), 0, stream>>>(w3, b3, act2, act3,  256,  512);
    fc_gemm<<<dim3(64, 2), dim3(256), 0, stream>>>(w4, b4, act3, act4,  128,  256);
    fc_final<<<dim3(64), dim3(256), 0, stream>>>(act4, w5, b5, (float*)d_out);
}